// Round 9
// baseline (386.530 us; speedup 1.0000x reference)
//
#include <hip/hip_runtime.h>
#include <math.h>

#define NRAD   12
#define NSPH   16
#define NTYPE  3
#define NATOM  1024
#define MAXNBR 32   // mean ~9.7 neighbors (RC=3.6, box 27.4^3); P(>32) ~ 1e-5
#define RCUT   3.6f
#define REPS   16   // diagnostic repetition factor (identical work each rep)

// LDS strides
#define RSTR   12
#define YSTR   16
#define CSTR   20   // 80B rows, 16B-aligned for ds_read_b128

#define NPAIR  144  // 12 n * 12 q

#define SQRT2F 1.41421356237309515f
#define LS1    0.57735026918962576f
#define LS2    0.44721359549995794f
#define LS3    0.37796447300922722f

struct SoapConsts {
    float norm[NRAD];
    float inv2sig2[NRAD];
    float sinv[NRAD * NRAD];
};

__device__ float g_posT[3][4 * NATOM];

static void compute_consts(SoapConsts* C) {
    double G[26];
    G[2] = 1.0;
    G[3] = 0.88622692545275801364908374167057259139877;
    for (int t = 4; t < 26; ++t) G[t] = (0.5 * t - 1.0) * G[t - 2];

    double sigma[NRAD], norm[NRAD];
    for (int n = 0; n < NRAD; ++n) {
        double sq = sqrt((double)n);
        if (sq < 1.0) sq = 1.0;
        sigma[n] = 3.6 * sq / 12.0;
        norm[n]  = 1.0 / sqrt(0.5 * G[2 * n + 3] * pow(sigma[n], 2.0 * n + 3.0));
    }

    double S[NRAD][NRAD];
    for (int i = 0; i < NRAD; ++i)
        for (int j = 0; j < NRAD; ++j) {
            double c = 0.5 / (sigma[i] * sigma[i]) + 0.5 / (sigma[j] * sigma[j]);
            double e = 0.5 * (i + j + 3.0);
            S[i][j]  = norm[i] * norm[j] * 0.5 * G[i + j + 3] * pow(c, -e);
        }

    double A[NRAD][NRAD], V[NRAD][NRAD];
    for (int i = 0; i < NRAD; ++i)
        for (int j = 0; j < NRAD; ++j) {
            A[i][j] = S[i][j];
            V[i][j] = (i == j) ? 1.0 : 0.0;
        }
    for (int sweep = 0; sweep < 60; ++sweep) {
        double off = 0.0;
        for (int p = 0; p < NRAD - 1; ++p)
            for (int q = p + 1; q < NRAD; ++q) off += A[p][q] * A[p][q];
        if (off < 1e-26) break;
        for (int p = 0; p < NRAD - 1; ++p) {
            for (int q = p + 1; q < NRAD; ++q) {
                double apq = A[p][q];
                if (fabs(apq) < 1e-300) continue;
                double tau = (A[q][q] - A[p][p]) / (2.0 * apq);
                double tt  = ((tau >= 0.0) ? 1.0 : -1.0) / (fabs(tau) + sqrt(1.0 + tau * tau));
                double cc  = 1.0 / sqrt(1.0 + tt * tt);
                double ss  = tt * cc;
                for (int k = 0; k < NRAD; ++k) {
                    double akp = A[k][p], akq = A[k][q];
                    A[k][p] = cc * akp - ss * akq;
                    A[k][q] = ss * akp + cc * akq;
                }
                for (int k = 0; k < NRAD; ++k) {
                    double apk = A[p][k], aqk = A[q][k];
                    A[p][k] = cc * apk - ss * aqk;
                    A[q][k] = ss * apk + cc * aqk;
                }
                for (int k = 0; k < NRAD; ++k) {
                    double vkp = V[k][p], vkq = V[k][q];
                    V[k][p] = cc * vkp - ss * vkq;
                    V[k][q] = ss * vkp + cc * vkq;
                }
            }
        }
    }
    double wisr[NRAD];
    for (int k = 0; k < NRAD; ++k) wisr[k] = 1.0 / sqrt(A[k][k]);
    for (int i = 0; i < NRAD; ++i)
        for (int j = 0; j < NRAD; ++j) {
            double s = 0.0;
            for (int k = 0; k < NRAD; ++k) s += V[i][k] * wisr[k] * V[j][k];
            C->sinv[i * NRAD + j] = (float)s;
        }
    for (int n = 0; n < NRAD; ++n) {
        C->norm[n]     = (float)norm[n];
        C->inv2sig2[n] = (float)(0.5 / (sigma[n] * sigma[n]));
    }
}

__global__ __launch_bounds__(256) void transpose_pos(const float* __restrict__ pos) {
    int tid = blockIdx.x * 256 + threadIdx.x;    // 0..4095
    const float* p = pos + 3 * tid;
    g_posT[0][tid] = p[0];
    g_posT[1][tid] = p[1];
    g_posT[2][tid] = p[2];
}

__device__ __forceinline__ void ldrow(const float* __restrict__ row, float* r) {
    const float4* p = reinterpret_cast<const float4*>(row);
    float4 a = p[0], b = p[1], c = p[2], d = p[3];
    r[0]=a.x;  r[1]=a.y;  r[2]=a.z;  r[3]=a.w;
    r[4]=b.x;  r[5]=b.y;  r[6]=b.z;  r[7]=b.w;
    r[8]=c.x;  r[9]=c.y;  r[10]=c.z; r[11]=c.w;
    r[12]=d.x; r[13]=d.y; r[14]=d.z; r[15]=d.w;
}

__device__ __forceinline__ float4 ld4(const float* p) {
    return *reinterpret_cast<const float4*>(p);
}

__device__ __forceinline__ float dot4l(const float* c1, const float* c2,
                                       float4 w4, float fact) {
    float d0 = c1[0]*c2[0];
    float d1 = c1[1]*c2[1] + c1[2]*c2[2] + c1[3]*c2[3];
    float d2 = c1[4]*c2[4] + c1[5]*c2[5] + c1[6]*c2[6] + c1[7]*c2[7]
             + c1[8]*c2[8];
    float d3 = c1[9]*c2[9] + c1[10]*c2[10] + c1[11]*c2[11] + c1[12]*c2[12]
             + c1[13]*c2[13] + c1[14]*c2[14] + c1[15]*c2[15];
    return fact * (w4.x * d0 + (LS1 * w4.y) * d1
                 + (LS2 * w4.z) * d2 + (LS3 * w4.w) * d3);
}

// ---------------------------------------------------------------------------
// DIAGNOSTIC: identical work repeated REPS times so the kernel's own counter
// row becomes visible above the harness fills, and dur_us delta isolates the
// per-rep kernel cost. out is rewritten with identical values each rep.
// ---------------------------------------------------------------------------
__global__ __launch_bounds__(64) void soap_kernel_x16(
    const int*   __restrict__ species,
    const float* __restrict__ W,
    const float* __restrict__ bias,
    float*       __restrict__ out,
    SoapConsts C)
{
    const int atom = blockIdx.x;
    const int b    = atom >> 10;
    const int i    = atom & (NATOM - 1);
    const int lane = threadIdx.x;

    const float* px = &g_posT[0][b * NATOM];
    const float* py = &g_posT[1][b * NATOM];
    const float* pz = &g_posT[2][b * NATOM];
    const float xi = px[i], yi = py[i], zi = pz[i];

    __shared__ int   nbPk[MAXNBR];
    __shared__ float nbR[MAXNBR][RSTR];
    __shared__ float nbY[MAXNBR][YSTR];
    __shared__ float cbuf[NTYPE][NRAD * CSTR];

    for (int rep = 0; rep < REPS; ++rep) {
        __syncthreads();   // protect LDS reuse across reps

        // ---- Phase A ----------------------------------------------------
        int nNbr = 0;
        const float rc2 = RCUT * RCUT;
        for (int base = 0; base < NATOM; base += 64) {
            int j = base + lane;
            float dx = xi - px[j];
            float dy = yi - py[j];
            float dz = zi - pz[j];
            float d2 = dx * dx + dy * dy + dz * dz;
            bool pred = (j != i) && (d2 < rc2);
            unsigned long long m = __ballot(pred);
            if (pred) {
                int slot = nNbr + __popcll(m & ((1ull << lane) - 1ull));
                if (slot < MAXNBR) nbPk[slot] = j;
            }
            nNbr += __popcll(m);
        }
        if (nNbr > MAXNBR) nNbr = MAXNBR;
        __syncthreads();

        // ---- Phase B ----------------------------------------------------
        if (lane < nNbr) {
            int j = nbPk[lane];
            float dx = xi - px[j];
            float dy = yi - py[j];
            float dz = zi - pz[j];
            float d2 = dx * dx + dy * dy + dz * dz;
            float d  = sqrtf(d2);
            float inv = 1.0f / d;
            float ux = dx * inv, uy = dy * inv, uz = dz * inv;

            float t = (d - (RCUT - 0.3f)) * (1.0f / 0.3f);
            t = fminf(fmaxf(t, 0.0f), 1.0f);
            float w = 0.5f * (1.0f + cosf(3.14159265358979323846f * t));

            float g[NRAD];
            float rp = 1.0f;
            #pragma unroll
            for (int n = 0; n < NRAD; ++n) {
                g[n] = C.norm[n] * rp * expf(-d2 * C.inv2sig2[n]) * w;
                rp *= d;
            }
            #pragma unroll
            for (int mm = 0; mm < NRAD; ++mm) {
                float s = 0.0f;
                #pragma unroll
                for (int n = 0; n < NRAD; ++n) s += g[n] * C.sinv[n * NRAD + mm];
                nbR[lane][mm] = s;
            }

            float x2 = ux * ux, y2 = uy * uy, z2 = uz * uz;
            nbY[lane][0]  = 0.28209479177387814f;
            nbY[lane][1]  = 0.4886025119029199f * uy;
            nbY[lane][2]  = 0.4886025119029199f * uz;
            nbY[lane][3]  = 0.4886025119029199f * ux;
            nbY[lane][4]  = 1.0925484305920792f * ux * uy;
            nbY[lane][5]  = 1.0925484305920792f * uy * uz;
            nbY[lane][6]  = 0.31539156525252005f * (3.0f * z2 - 1.0f);
            nbY[lane][7]  = 1.0925484305920792f * ux * uz;
            nbY[lane][8]  = 0.5462742152960396f * (x2 - y2);
            nbY[lane][9]  = 0.5900435899266435f * uy * (3.0f * x2 - y2);
            nbY[lane][10] = 2.890611442640554f * ux * uy * uz;
            nbY[lane][11] = 0.4570457994644658f * uy * (5.0f * z2 - 1.0f);
            nbY[lane][12] = 0.3731763325901154f * uz * (5.0f * z2 - 3.0f);
            nbY[lane][13] = 0.4570457994644658f * ux * (5.0f * z2 - 1.0f);
            nbY[lane][14] = 1.445305721320277f * uz * (x2 - y2);
            nbY[lane][15] = 0.5900435899266435f * ux * (3.0f * x2 - y2);
            nbPk[lane] = j | (species[b * NATOM + j] << 16);
        }
        __syncthreads();

        // ---- Phase C ----------------------------------------------------
        float a0[3], a1_[3], a2_[3];
        int mI[3], kI[3];
        #pragma unroll
        for (int t = 0; t < 3; ++t) {
            a0[t] = a1_[t] = a2_[t] = 0.0f;
            int mk = lane + t * 64;
            mI[t] = mk >> 4;
            kI[t] = mk & 15;
        }
        for (int j = 0; j < nNbr; ++j) {
            int sp = nbPk[j] >> 16;
            #pragma unroll
            for (int t = 0; t < 3; ++t) {
                float v = nbR[j][mI[t]] * nbY[j][kI[t]];
                a0[t]  += (sp == 0) ? v : 0.0f;
                a1_[t] += (sp == 1) ? v : 0.0f;
                a2_[t] += (sp == 2) ? v : 0.0f;
            }
        }
        #pragma unroll
        for (int t = 0; t < 3; ++t) {
            cbuf[0][mI[t] * CSTR + kI[t]] = a0[t];
            cbuf[1][mI[t] * CSTR + kI[t]] = a1_[t];
            cbuf[2][mI[t] * CSTR + kI[t]] = a2_[t];
        }
        __syncthreads();

        // ---- Phase D ----------------------------------------------------
        float partial = 0.0f;
        #pragma unroll 1
        for (int t = 0; t < 3; ++t) {
            int pi  = lane + (t << 6);
            bool act = (pi < NPAIR);
            int piC = act ? pi : 0;
            int n = piC / 12;
            int q = piC - 12 * n;
            const float* wbase = W + n * 48 + q * 4;

            float A_[16], B_[16], Cv[16];
            float acc = 0.0f;
            ldrow(&cbuf[0][n * CSTR], A_);
            ldrow(&cbuf[0][q * CSTR], B_);
            ldrow(&cbuf[2][q * CSTR], Cv);
            acc += dot4l(A_, B_, ld4(wbase + 0 * 576), 1.0f);
            ldrow(&cbuf[1][q * CSTR], B_);
            acc += dot4l(A_, B_, ld4(wbase + 1 * 576), SQRT2F);
            acc += dot4l(A_, Cv, ld4(wbase + 2 * 576), SQRT2F);
            ldrow(&cbuf[1][n * CSTR], A_);
            acc += dot4l(A_, B_, ld4(wbase + 3 * 576), 1.0f);
            acc += dot4l(A_, Cv, ld4(wbase + 4 * 576), SQRT2F);
            ldrow(&cbuf[2][n * CSTR], A_);
            acc += dot4l(A_, Cv, ld4(wbase + 5 * 576), 1.0f);

            partial += act ? acc : 0.0f;
        }

        #pragma unroll
        for (int off = 32; off > 0; off >>= 1)
            partial += __shfl_down(partial, off, 64);
        if (lane == 0) out[atom] = partial + bias[0];
    }
}

extern "C" void kernel_launch(void* const* d_in, const int* in_sizes, int n_in,
                              void* d_out, int out_size, void* d_ws, size_t ws_size,
                              hipStream_t stream) {
    const float* positions = (const float*)d_in[0];
    const int*   species   = (const int*)d_in[1];
    const float* W         = (const float*)d_in[2];
    const float* bias      = (const float*)d_in[3];
    float*       out       = (float*)d_out;

    SoapConsts C;
    compute_consts(&C);

    int nAtoms = in_sizes[0] / 3;                      // 4096
    transpose_pos<<<nAtoms / 256, 256, 0, stream>>>(positions);
    soap_kernel_x16<<<nAtoms, 64, 0, stream>>>(species, W, bias, out, C);
}

// Round 12
// 72.297 us; speedup vs baseline: 5.3464x; 5.3464x over previous
//
#include <hip/hip_runtime.h>
#include <math.h>

#define NRAD   12
#define NSPH   16
#define NTYPE  3
#define NATOM  1024
#define MAXNBR 32   // mean ~9.7 neighbors; P(>32) ~ 1e-5
#define RCUT   3.6f
#define APB    4    // atoms (waves) per block

// LDS strides
#define RSTR   12
#define YSTR   16
#define CSTR   20   // 80B rows, 16B-aligned for ds_read_b128

#define NPAIR  144  // 12 n * 12 q

#define SQRT2F 1.41421356237309515f
#define LS1    0.57735026918962576f
#define LS2    0.44721359549995794f
#define LS3    0.37796447300922722f

struct SoapConsts {
    float norm[NRAD];
    float inv2sig2[NRAD];
    float sinv[NRAD * NRAD];
};

static void compute_consts(SoapConsts* C) {
    double G[26];
    G[2] = 1.0;
    G[3] = 0.88622692545275801364908374167057259139877;
    for (int t = 4; t < 26; ++t) G[t] = (0.5 * t - 1.0) * G[t - 2];

    double sigma[NRAD], norm[NRAD];
    for (int n = 0; n < NRAD; ++n) {
        double sq = sqrt((double)n);
        if (sq < 1.0) sq = 1.0;
        sigma[n] = 3.6 * sq / 12.0;
        norm[n]  = 1.0 / sqrt(0.5 * G[2 * n + 3] * pow(sigma[n], 2.0 * n + 3.0));
    }

    double S[NRAD][NRAD];
    for (int i = 0; i < NRAD; ++i)
        for (int j = 0; j < NRAD; ++j) {
            double c = 0.5 / (sigma[i] * sigma[i]) + 0.5 / (sigma[j] * sigma[j]);
            double e = 0.5 * (i + j + 3.0);
            S[i][j]  = norm[i] * norm[j] * 0.5 * G[i + j + 3] * pow(c, -e);
        }

    double A[NRAD][NRAD], V[NRAD][NRAD];
    for (int i = 0; i < NRAD; ++i)
        for (int j = 0; j < NRAD; ++j) {
            A[i][j] = S[i][j];
            V[i][j] = (i == j) ? 1.0 : 0.0;
        }
    for (int sweep = 0; sweep < 60; ++sweep) {
        double off = 0.0;
        for (int p = 0; p < NRAD - 1; ++p)
            for (int q = p + 1; q < NRAD; ++q) off += A[p][q] * A[p][q];
        if (off < 1e-26) break;
        for (int p = 0; p < NRAD - 1; ++p) {
            for (int q = p + 1; q < NRAD; ++q) {
                double apq = A[p][q];
                if (fabs(apq) < 1e-300) continue;
                double tau = (A[q][q] - A[p][p]) / (2.0 * apq);
                double tt  = ((tau >= 0.0) ? 1.0 : -1.0) / (fabs(tau) + sqrt(1.0 + tau * tau));
                double cc  = 1.0 / sqrt(1.0 + tt * tt);
                double ss  = tt * cc;
                for (int k = 0; k < NRAD; ++k) {
                    double akp = A[k][p], akq = A[k][q];
                    A[k][p] = cc * akp - ss * akq;
                    A[k][q] = ss * akp + cc * akq;
                }
                for (int k = 0; k < NRAD; ++k) {
                    double apk = A[p][k], aqk = A[q][k];
                    A[p][k] = cc * apk - ss * aqk;
                    A[q][k] = ss * apk + cc * aqk;
                }
                for (int k = 0; k < NRAD; ++k) {
                    double vkp = V[k][p], vkq = V[k][q];
                    V[k][p] = cc * vkp - ss * vkq;
                    V[k][q] = ss * vkp + cc * vkq;
                }
            }
        }
    }
    double wisr[NRAD];
    for (int k = 0; k < NRAD; ++k) wisr[k] = 1.0 / sqrt(A[k][k]);
    for (int i = 0; i < NRAD; ++i)
        for (int j = 0; j < NRAD; ++j) {
            double s = 0.0;
            for (int k = 0; k < NRAD; ++k) s += V[i][k] * wisr[k] * V[j][k];
            C->sinv[i * NRAD + j] = (float)s;
        }
    for (int n = 0; n < NRAD; ++n) {
        C->norm[n]     = (float)norm[n];
        C->inv2sig2[n] = (float)(0.5 / (sigma[n] * sigma[n]));
    }
}

__device__ __forceinline__ void ldrow(const float* __restrict__ row, float* r) {
    const float4* p = reinterpret_cast<const float4*>(row);
    float4 a = p[0], b = p[1], c = p[2], d = p[3];
    r[0]=a.x;  r[1]=a.y;  r[2]=a.z;  r[3]=a.w;
    r[4]=b.x;  r[5]=b.y;  r[6]=b.z;  r[7]=b.w;
    r[8]=c.x;  r[9]=c.y;  r[10]=c.z; r[11]=c.w;
    r[12]=d.x; r[13]=d.y; r[14]=d.z; r[15]=d.w;
}

__device__ __forceinline__ float4 ld4(const float* p) {
    return *reinterpret_cast<const float4*>(p);
}

__device__ __forceinline__ float dot4l(const float* c1, const float* c2,
                                       float4 w4, float fact) {
    float d0 = c1[0]*c2[0];
    float d1 = c1[1]*c2[1] + c1[2]*c2[2] + c1[3]*c2[3];
    float d2 = c1[4]*c2[4] + c1[5]*c2[5] + c1[6]*c2[6] + c1[7]*c2[7]
             + c1[8]*c2[8];
    float d3 = c1[9]*c2[9] + c1[10]*c2[10] + c1[11]*c2[11] + c1[12]*c2[12]
             + c1[13]*c2[13] + c1[14]*c2[14] + c1[15]*c2[15];
    return fact * (w4.x * d0 + (LS1 * w4.y) * d1
                 + (LS2 * w4.z) * d2 + (LS3 * w4.w) * d3);
}

// ---------------------------------------------------------------------------
// 4 atoms per 256-thread block (one wave per atom). Batch positions staged
// once per block into LDS SoA. 1024 blocks total. LDS ~37.9KB -> 4 blocks/CU
// = 16 waves/CU (4/SIMD), vs ~6.4 waves/CU measured for 1-wave blocks (r9
// diagnostic: OccupancyPercent ~20% was the binding constraint).
// ---------------------------------------------------------------------------
__global__ __launch_bounds__(256, 4) void soap_kernel(
    const float* __restrict__ positions,  // (4,1024,3)
    const int*   __restrict__ species,    // (4,1024)
    const float* __restrict__ W,          // (3456)
    const float* __restrict__ bias,       // (1)
    float*       __restrict__ out,        // (4096)
    SoapConsts C)
{
    const int wid  = threadIdx.x >> 6;            // wave id = which atom
    const int lane = threadIdx.x & 63;
    const int atom = blockIdx.x * APB + wid;      // 4 atoms, same batch
    const int b    = atom >> 10;
    const int i    = atom & (NATOM - 1);

    __shared__ float pbuf[3][NATOM];              // 12KB batch positions SoA
    __shared__ int   nbPk[APB][MAXNBR];
    __shared__ float nbR[APB][MAXNBR][RSTR];
    __shared__ float nbY[APB][MAXNBR][YSTR];
    __shared__ float cbuf[APB][NTYPE][NRAD * CSTR];

    // ---- Stage positions: AoS global -> SoA LDS (float4 chunks) ----------
    {
        const float4* aos4 = reinterpret_cast<const float4*>(positions + b * NATOM * 3);
        for (int idx = threadIdx.x; idx < NATOM * 3 / 4; idx += 256) {
            float4 v = aos4[idx];
            int f0 = idx * 4;
            #pragma unroll
            for (int c = 0; c < 4; ++c) {
                int f = f0 + c;
                int j = f / 3;
                int comp = f - 3 * j;
                float val = (c == 0) ? v.x : (c == 1) ? v.y : (c == 2) ? v.z : v.w;
                pbuf[comp][j] = val;
            }
        }
    }
    __syncthreads();

    const float xi = pbuf[0][i], yi = pbuf[1][i], zi = pbuf[2][i];

    // ---- Phase A: ballot-compacted neighbor scan (LDS SoA reads) ---------
    int nNbr = 0;
    const float rc2 = RCUT * RCUT;
    for (int base = 0; base < NATOM; base += 64) {
        int j = base + lane;
        float dx = xi - pbuf[0][j];
        float dy = yi - pbuf[1][j];
        float dz = zi - pbuf[2][j];
        float d2 = dx * dx + dy * dy + dz * dz;
        bool pred = (j != i) && (d2 < rc2);
        unsigned long long m = __ballot(pred);
        if (pred) {
            int slot = nNbr + __popcll(m & ((1ull << lane) - 1ull));
            if (slot < MAXNBR) nbPk[wid][slot] = j;
        }
        nNbr += __popcll(m);
    }
    if (nNbr > MAXNBR) nNbr = MAXNBR;
    __syncthreads();

    // ---- Phase B: per-neighbor radial basis + spherical harmonics --------
    if (lane < nNbr) {
        int j = nbPk[wid][lane];
        float dx = xi - pbuf[0][j];
        float dy = yi - pbuf[1][j];
        float dz = zi - pbuf[2][j];
        float d2 = dx * dx + dy * dy + dz * dz;
        float d  = sqrtf(d2);
        float inv = 1.0f / d;
        float ux = dx * inv, uy = dy * inv, uz = dz * inv;

        float t = (d - (RCUT - 0.3f)) * (1.0f / 0.3f);
        t = fminf(fmaxf(t, 0.0f), 1.0f);
        float w = 0.5f * (1.0f + cosf(3.14159265358979323846f * t));

        float g[NRAD];
        float rp = 1.0f;
        #pragma unroll
        for (int n = 0; n < NRAD; ++n) {
            g[n] = C.norm[n] * rp * expf(-d2 * C.inv2sig2[n]) * w;
            rp *= d;
        }
        #pragma unroll
        for (int mm = 0; mm < NRAD; ++mm) {
            float s = 0.0f;
            #pragma unroll
            for (int n = 0; n < NRAD; ++n) s += g[n] * C.sinv[n * NRAD + mm];
            nbR[wid][lane][mm] = s;
        }

        float x2 = ux * ux, y2 = uy * uy, z2 = uz * uz;
        nbY[wid][lane][0]  = 0.28209479177387814f;
        nbY[wid][lane][1]  = 0.4886025119029199f * uy;
        nbY[wid][lane][2]  = 0.4886025119029199f * uz;
        nbY[wid][lane][3]  = 0.4886025119029199f * ux;
        nbY[wid][lane][4]  = 1.0925484305920792f * ux * uy;
        nbY[wid][lane][5]  = 1.0925484305920792f * uy * uz;
        nbY[wid][lane][6]  = 0.31539156525252005f * (3.0f * z2 - 1.0f);
        nbY[wid][lane][7]  = 1.0925484305920792f * ux * uz;
        nbY[wid][lane][8]  = 0.5462742152960396f * (x2 - y2);
        nbY[wid][lane][9]  = 0.5900435899266435f * uy * (3.0f * x2 - y2);
        nbY[wid][lane][10] = 2.890611442640554f * ux * uy * uz;
        nbY[wid][lane][11] = 0.4570457994644658f * uy * (5.0f * z2 - 1.0f);
        nbY[wid][lane][12] = 0.3731763325901154f * uz * (5.0f * z2 - 3.0f);
        nbY[wid][lane][13] = 0.4570457994644658f * ux * (5.0f * z2 - 1.0f);
        nbY[wid][lane][14] = 1.445305721320277f * uz * (x2 - y2);
        nbY[wid][lane][15] = 0.5900435899266435f * ux * (3.0f * x2 - y2);
        nbPk[wid][lane] = j | (species[b * NATOM + j] << 16);
    }
    __syncthreads();

    // ---- Phase C: accumulate c[3][12][16]; lane owns 3 (m,k) slots -------
    float a0[3], a1_[3], a2_[3];
    int mI[3], kI[3];
    #pragma unroll
    for (int t = 0; t < 3; ++t) {
        a0[t] = a1_[t] = a2_[t] = 0.0f;
        int mk = lane + t * 64;
        mI[t] = mk >> 4;
        kI[t] = mk & 15;
    }
    for (int j = 0; j < nNbr; ++j) {
        int sp = nbPk[wid][j] >> 16;
        #pragma unroll
        for (int t = 0; t < 3; ++t) {
            float v = nbR[wid][j][mI[t]] * nbY[wid][j][kI[t]];
            a0[t]  += (sp == 0) ? v : 0.0f;
            a1_[t] += (sp == 1) ? v : 0.0f;
            a2_[t] += (sp == 2) ? v : 0.0f;
        }
    }
    #pragma unroll
    for (int t = 0; t < 3; ++t) {
        cbuf[wid][0][mI[t] * CSTR + kI[t]] = a0[t];
        cbuf[wid][1][mI[t] * CSTR + kI[t]] = a1_[t];
        cbuf[wid][2][mI[t] * CSTR + kI[t]] = a2_[t];
    }
    __syncthreads();

    // ---- Phase D: pair-major, 3-buffer streaming b128 row loads ----------
    float partial = 0.0f;
    #pragma unroll 1
    for (int t = 0; t < 3; ++t) {
        int pi  = lane + (t << 6);
        bool act = (pi < NPAIR);
        int piC = act ? pi : 0;
        int n = piC / 12;
        int q = piC - 12 * n;
        const float* wbase = W + n * 48 + q * 4;

        float A_[16], B_[16], Cv[16];
        float acc = 0.0f;
        ldrow(&cbuf[wid][0][n * CSTR], A_);
        ldrow(&cbuf[wid][0][q * CSTR], B_);
        ldrow(&cbuf[wid][2][q * CSTR], Cv);
        acc += dot4l(A_, B_, ld4(wbase + 0 * 576), 1.0f);
        ldrow(&cbuf[wid][1][q * CSTR], B_);
        acc += dot4l(A_, B_, ld4(wbase + 1 * 576), SQRT2F);
        acc += dot4l(A_, Cv, ld4(wbase + 2 * 576), SQRT2F);
        ldrow(&cbuf[wid][1][n * CSTR], A_);
        acc += dot4l(A_, B_, ld4(wbase + 3 * 576), 1.0f);
        acc += dot4l(A_, Cv, ld4(wbase + 4 * 576), SQRT2F);
        ldrow(&cbuf[wid][2][n * CSTR], A_);
        acc += dot4l(A_, Cv, ld4(wbase + 5 * 576), 1.0f);

        partial += act ? acc : 0.0f;
    }

    #pragma unroll
    for (int off = 32; off > 0; off >>= 1)
        partial += __shfl_down(partial, off, 64);
    if (lane == 0) out[atom] = partial + bias[0];
}

extern "C" void kernel_launch(void* const* d_in, const int* in_sizes, int n_in,
                              void* d_out, int out_size, void* d_ws, size_t ws_size,
                              hipStream_t stream) {
    const float* positions = (const float*)d_in[0];   // (4,1024,3) f32
    const int*   species   = (const int*)d_in[1];     // (4,1024)   i32
    const float* W         = (const float*)d_in[2];   // (3456)     f32
    const float* bias      = (const float*)d_in[3];   // (1)        f32
    float*       out       = (float*)d_out;           // (4096,1)   f32

    SoapConsts C;
    compute_consts(&C);

    int nAtoms  = in_sizes[0] / 3;                    // 4096
    int nBlocks = nAtoms / APB;                       // 1024
    soap_kernel<<<nBlocks, 64 * APB, 0, stream>>>(positions, species, W, bias, out, C);
}